// Round 4
// baseline (209.981 us; speedup 1.0000x reference)
//
#include <hip/hip_runtime.h>
#include <hip/hip_bf16.h>
#include <stdint.h>

// Problem constants (B=2, L=2048, D=2048, E=8, Dg=256, k=2)
#define T_TOK 4096
#define DIM   2048
#define NEXP  8
#define DG    256
#define TOPK  2

// GEMM tiling: 128x128 block tile, 4 waves of 64x64, BK=32
#define BM 128
#define BN 128
#define BK 32
#define NROWS  (T_TOK*TOPK + NEXP*BM)   // 9216 padded row capacity
#define NBLK_M (NROWS/BM)               // 72 M-blocks
#define KSPLIT 4                        // down GEMM split-K factor

typedef __attribute__((ext_vector_type(8))) short short8;
typedef __attribute__((ext_vector_type(4))) float f32x4;

static __device__ __forceinline__ short f2bf(float f) {
    union { float f; uint32_t u; } v{f};
    uint32_t r = v.u + 0x7fffu + ((v.u >> 16) & 1u);   // RNE
    return (short)(r >> 16);
}
static __device__ __forceinline__ float b2f(short s) {
    union { uint32_t u; float f; } v{((uint32_t)(unsigned short)s) << 16};
    return v.f;
}
static __device__ __forceinline__ short8 pack8(float4 a, float4 b) {
    short8 o;
    o[0] = f2bf(a.x); o[1] = f2bf(a.y); o[2] = f2bf(a.z); o[3] = f2bf(a.w);
    o[4] = f2bf(b.x); o[5] = f2bf(b.y); o[6] = f2bf(b.z); o[7] = f2bf(b.w);
    return o;
}

#define GLD16(g, l) \
    __builtin_amdgcn_global_load_lds((const __attribute__((address_space(1))) void*)(g), \
                                     (__attribute__((address_space(3))) void*)(l), 16, 0, 0)

// ---------------------------------------------------------------------------
// Gate + x->bf16 fusion. One wave per token; 8 per-expert accumulators and a
// single interleaved butterfly (8 independent shuffle chains).
// ---------------------------------------------------------------------------
__global__ __launch_bounds__(256) void gate_kernel(const float* __restrict__ x,
                                                   const float* __restrict__ Wg,
                                                   int* __restrict__ gidx,
                                                   float* __restrict__ gval,
                                                   short* __restrict__ x_bf)
{
    int token = blockIdx.x * 4 + (threadIdx.x >> 6);
    int lane  = threadIdx.x & 63;
    const float4* xr = (const float4*)(x + (size_t)token * DIM);

    float4 xv[8];
#pragma unroll
    for (int i = 0; i < 8; i++) xv[i] = xr[lane + 64 * i];

    short4* xb = (short4*)(x_bf + (size_t)token * DIM);
#pragma unroll
    for (int i = 0; i < 8; i++) {
        short4 o;
        o.x = f2bf(xv[i].x); o.y = f2bf(xv[i].y);
        o.z = f2bf(xv[i].z); o.w = f2bf(xv[i].w);
        xb[lane + 64 * i] = o;
    }

    float acc[NEXP];
#pragma unroll
    for (int e = 0; e < NEXP; e++) {
        const float4* wr = (const float4*)(Wg + e * DIM);
        float a = 0.0f;
#pragma unroll
        for (int i = 0; i < 8; i++) {
            float4 w = wr[lane + 64 * i];
            a += xv[i].x * w.x + xv[i].y * w.y + xv[i].z * w.z + xv[i].w * w.w;
        }
        acc[e] = a;
    }

#pragma unroll
    for (int m = 1; m < 64; m <<= 1) {
#pragma unroll
        for (int e = 0; e < NEXP; e++) acc[e] += __shfl_xor(acc[e], m, 64);
    }

    if (lane == 0) {
        float sg[NEXP];
#pragma unroll
        for (int e = 0; e < NEXP; e++) sg[e] = 1.0f / (1.0f + expf(-acc[e]));
        int i0 = 0;
#pragma unroll
        for (int e = 1; e < NEXP; e++) if (sg[e] > sg[i0]) i0 = e;   // strict >: lowest index wins
        int i1 = (i0 == 0) ? 1 : 0;
#pragma unroll
        for (int e = 0; e < NEXP; e++) if (e != i0 && e != i1 && sg[e] > sg[i1]) i1 = e;
        gidx[2 * token + 0] = i0;
        gidx[2 * token + 1] = i1;
        gval[2 * token + 0] = sg[i0];
        gval[2 * token + 1] = sg[i1];
    }
}

// ---------------------------------------------------------------------------
// Bucket rows by expert (segments padded to BM=128); forward map rowtok and
// inverse map rowpos[2t+s]. Single block, 1024 threads.
// ---------------------------------------------------------------------------
__global__ __launch_bounds__(1024) void bucket_kernel(const int* __restrict__ gidx,
                                                      int* __restrict__ rowtok,
                                                      int* __restrict__ rowpos,
                                                      int* __restrict__ seg_off)
{
    __shared__ int cnt[NEXP];
    __shared__ int cur[NEXP];
    int tid = threadIdx.x;
    if (tid < NEXP) cnt[tid] = 0;
    __syncthreads();

    for (int t = tid; t < T_TOK; t += 1024) {
        atomicAdd(&cnt[gidx[2 * t + 0]], 1);
        atomicAdd(&cnt[gidx[2 * t + 1]], 1);
    }
    __syncthreads();

    if (tid == 0) {
        int o = 0;
        for (int e = 0; e < NEXP; e++) {
            seg_off[e] = o;
            cur[e] = o;
            o += ((cnt[e] + BM - 1) / BM) * BM;
        }
        seg_off[NEXP] = o;
    }
    __syncthreads();

    for (int r = tid; r < NROWS; r += 1024) rowtok[r] = -1;
    __syncthreads();

    for (int t = tid; t < T_TOK; t += 1024) {
        for (int s = 0; s < TOPK; s++) {
            int e = gidx[2 * t + s];
            int p = atomicAdd(&cur[e], 1);
            rowtok[p] = t;
            rowpos[2 * t + s] = p;
        }
    }
}

// ---------------------------------------------------------------------------
// Unified grouped GEMM (bf16 MFMA), 128x128 tile, 4 waves x 64x64 each.
//   A[row][k]: bf16 token rows gathered via rowtok (GLD16 staging).
//   B[e][n][k]: fp32 weights, converted inline to bf16 and staged via
//               swizzled ds_write_b128 (software-prefetched one step ahead).
//   PART=true : write fp32 partials P[kb][row][n]  (split-K, down GEMM)
//   PART=false: write bf16 C[row][n]               (up GEMM)
// LDS chunk XOR swizzle: LDS[row][c] holds global chunk c ^ ((row>>1)&3),
// making the 8 ds_read_b128 fragment reads per K-step <=2-way (free).
// ---------------------------------------------------------------------------
template<int K, int KC, int Ntot, bool PART>
__global__ __launch_bounds__(256) void gemm_kernel(const short* __restrict__ A,
                                                   const float* __restrict__ Bf,
                                                   const int* __restrict__ rowtok,
                                                   const int* __restrict__ seg_off,
                                                   short* __restrict__ Cbf,
                                                   float* __restrict__ Cf32)
{
    __shared__ short As[BM][BK];   // 8 KB
    __shared__ short Bs[BN][BK];   // 8 KB

    int row0 = blockIdx.x * BM;
    if (row0 >= seg_off[NEXP]) return;
    int e = 0;
    while (row0 >= seg_off[e + 1]) ++e;   // BM-padded segments: block in one expert
    int n0 = blockIdx.y * BN;
    int kb = blockIdx.z;
    int k_start = kb * KC;

    int tid = threadIdx.x;
    int w = tid >> 6, l = tid & 63;

    // ---- A staging: 2 GLD16 per lane cover 128 rows x 32 k ----
    int r = l >> 2, c = l & 3;
    int gch = c ^ ((r >> 1) & 3);              // global chunk for LDS chunk c
    int ar0 = w * 16 + r, ar1 = 64 + w * 16 + r;
    int ta0 = rowtok[row0 + ar0]; if (ta0 < 0) ta0 = 0;
    int ta1 = rowtok[row0 + ar1]; if (ta1 < 0) ta1 = 0;
    const short* ag0 = A + (size_t)ta0 * K + k_start + gch * 8;
    const short* ag1 = A + (size_t)ta1 * K + k_start + gch * 8;
    auto ldsA0 = (__attribute__((address_space(3))) void*)&As[w * 16][0];
    auto ldsA1 = (__attribute__((address_space(3))) void*)&As[64 + w * 16][0];

    // ---- B staging: thread = (row bn, half h); 16 fp32 -> 16 bf16 ----
    int bn = tid >> 1, h = tid & 1;
    const float4* bg = (const float4*)(Bf + (size_t)e * Ntot * K
                                          + (size_t)(n0 + bn) * K + k_start + h * 16);
    int sw = (bn >> 1) & 3;
    short* bs0 = &Bs[bn][((2 * h + 0) ^ sw) * 8];
    short* bs1 = &Bs[bn][((2 * h + 1) ^ sw) * 8];

    // ---- fragment read addresses ----
    int mlane = l & 15, q = l >> 4;
    int rA = (q ^ ((mlane >> 1) & 3)) * 8;     // swizzled chunk offset (shorts)
    int wm = w >> 1, wn = w & 1;
    const short* pA = &As[wm * 64 + mlane][0] + rA;
    const short* pB = &Bs[wn * 64 + mlane][0] + rA;

    f32x4 acc[4][4] = {};

    // prefetch B regs for step 0
    float4 br0 = bg[0], br1 = bg[1], br2 = bg[2], br3 = bg[3];
    bg += 8;   // 32 floats

    constexpr int NS = KC / BK;
    for (int t = 0; t < NS; ++t) {
        GLD16(ag0, ldsA0);
        GLD16(ag1, ldsA1);
        ag0 += BK; ag1 += BK;

        *(short8*)bs0 = pack8(br0, br1);
        *(short8*)bs1 = pack8(br2, br3);
        if (t + 1 < NS) { br0 = bg[0]; br1 = bg[1]; br2 = bg[2]; br3 = bg[3]; bg += 8; }
        __syncthreads();   // drains GLD16 (vmcnt) + ds_writes before reads

        short8 a[4], b[4];
#pragma unroll
        for (int i = 0; i < 4; i++) a[i] = *(const short8*)(pA + i * 16 * BK);
#pragma unroll
        for (int j = 0; j < 4; j++) b[j] = *(const short8*)(pB + j * 16 * BK);

#pragma unroll
        for (int i = 0; i < 4; i++)
#pragma unroll
            for (int j = 0; j < 4; j++)
                acc[i][j] = __builtin_amdgcn_mfma_f32_16x16x32_bf16(a[i], b[j], acc[i][j], 0, 0, 0);
        __syncthreads();   // all reads done before next overwrite
    }

    // epilogue: D layout col = lane&15, row = (lane>>4)*4 + reg  [m89-verified]
#pragma unroll
    for (int i = 0; i < 4; i++) {
        int rbase = row0 + wm * 64 + i * 16 + q * 4;
#pragma unroll
        for (int j = 0; j < 4; j++) {
            int col = n0 + wn * 64 + j * 16 + mlane;
#pragma unroll
            for (int rr = 0; rr < 4; rr++) {
                if (PART)
                    Cf32[((size_t)kb * NROWS + (rbase + rr)) * Ntot + col] = acc[i][j][rr];
                else
                    Cbf[(size_t)(rbase + rr) * Ntot + col] = f2bf(acc[i][j][rr]);
            }
        }
    }
}

// ---------------------------------------------------------------------------
// Combine down partials -> per-token down (fp32 gates + split-K reduce),
// emit bf16 for up GEMM. One wave per token (4 tokens / block).
// ---------------------------------------------------------------------------
__global__ __launch_bounds__(256) void combine1_kernel(const float* __restrict__ P,
                                                       const int* __restrict__ rowpos,
                                                       const float* __restrict__ gval,
                                                       short* __restrict__ dt)
{
    int t = blockIdx.x * 4 + (threadIdx.x >> 6);
    int d = threadIdx.x & 63;                  // float4 index within DG
    int   p0 = rowpos[2 * t], p1 = rowpos[2 * t + 1];
    float g0 = gval[2 * t],   g1 = gval[2 * t + 1];
    const float4* P4 = (const float4*)P;
    const size_t plane = (size_t)NROWS * DG / 4;   // float4 per kb plane

    float4 s0 = {0, 0, 0, 0}, s1 = {0, 0, 0, 0};
#pragma unroll
    for (int kb = 0; kb < KSPLIT; kb++) {
        float4 a = P4[kb * plane + (size_t)p0 * (DG / 4) + d];
        float4 b = P4[kb * plane + (size_t)p1 * (DG / 4) + d];
        s0.x += a.x; s0.y += a.y; s0.z += a.z; s0.w += a.w;
        s1.x += b.x; s1.y += b.y; s1.z += b.z; s1.w += b.w;
    }
    short4 o;
    o.x = f2bf(g0 * s0.x + g1 * s1.x);
    o.y = f2bf(g0 * s0.y + g1 * s1.y);
    o.z = f2bf(g0 * s0.z + g1 * s1.z);
    o.w = f2bf(g0 * s0.w + g1 * s1.w);
    ((short4*)(dt + (size_t)t * DG))[d] = o;
}

// ---------------------------------------------------------------------------
// Combine up rows -> final output (fp32). short4-vectorized.
// ---------------------------------------------------------------------------
__global__ __launch_bounds__(256) void combine2_kernel(const short* __restrict__ ur,
                                                       const int* __restrict__ rowpos,
                                                       const float* __restrict__ gval,
                                                       float* __restrict__ out)
{
    int i = blockIdx.x * 256 + threadIdx.x;       // i < T*D/4
    int t = i >> 9;                               // D/4 = 512
    int c = (i & 511) * 4;
    int   p0 = rowpos[2 * t], p1 = rowpos[2 * t + 1];
    float g0 = gval[2 * t],   g1 = gval[2 * t + 1];
    short4 u0 = *(const short4*)&ur[(size_t)p0 * DIM + c];
    short4 u1 = *(const short4*)&ur[(size_t)p1 * DIM + c];
    float4 o;
    o.x = g0 * b2f(u0.x) + g1 * b2f(u1.x);
    o.y = g0 * b2f(u0.y) + g1 * b2f(u1.y);
    o.z = g0 * b2f(u0.z) + g1 * b2f(u1.z);
    o.w = g0 * b2f(u0.w) + g1 * b2f(u1.w);
    *(float4*)&out[(size_t)t * DIM + c] = o;
}

// ---------------------------------------------------------------------------
// Workspace layout (bytes), ~95 MB total:
//   gidx 0 | gval 32768 | rowtok 65536 | rowpos 102400 | seg_off 135168
//   x_bf 135424 (16.8MB) | dr_part 16912640 (37.7MB fp32)
//   dt_bf 54661376 (2MB) | ur_bf 56758528 (37.7MB)
// ---------------------------------------------------------------------------
extern "C" void kernel_launch(void* const* d_in, const int* in_sizes, int n_in,
                              void* d_out, int out_size, void* d_ws, size_t ws_size,
                              hipStream_t stream) {
    const float* x  = (const float*)d_in[0];
    const float* Wg = (const float*)d_in[1];
    const float* Wd = (const float*)d_in[2];
    const float* Wu = (const float*)d_in[3];
    float* out = (float*)d_out;

    char* p = (char*)d_ws;
    int*   gidx    = (int*)(p + 0);
    float* gval    = (float*)(p + 32768);
    int*   rowtok  = (int*)(p + 65536);
    int*   rowpos  = (int*)(p + 102400);
    int*   seg_off = (int*)(p + 135168);
    short* x_bf    = (short*)(p + 135424);
    float* dr_part = (float*)(p + 16912640);
    short* dt_bf   = (short*)(p + 54661376);
    short* ur_bf   = (short*)(p + 56758528);

    gate_kernel<<<T_TOK / 4, 256, 0, stream>>>(x, Wg, gidx, gval, x_bf);
    bucket_kernel<<<1, 1024, 0, stream>>>(gidx, rowtok, rowpos, seg_off);

    // down: M=9216, N=256, K=2048, split-K=4 -> fp32 partials
    gemm_kernel<DIM, DIM / KSPLIT, DG, true>
        <<<dim3(NBLK_M, DG / BN, KSPLIT), 256, 0, stream>>>(
            x_bf, Wd, rowtok, seg_off, nullptr, dr_part);
    combine1_kernel<<<T_TOK / 4, 256, 0, stream>>>(dr_part, rowpos, gval, dt_bf);

    // up: M=9216, N=2048, K=256 -> bf16 rows
    gemm_kernel<DG, DG, DIM, false>
        <<<dim3(NBLK_M, DIM / BN, 1), 256, 0, stream>>>(
            dt_bf, Wu, rowtok, seg_off, ur_bf, nullptr);
    combine2_kernel<<<T_TOK * DIM / 4 / 256, 256, 0, stream>>>(ur_bf, rowpos, gval, out);
}

// Round 5
// 201.794 us; speedup vs baseline: 1.0406x; 1.0406x over previous
//
#include <hip/hip_runtime.h>
#include <hip/hip_bf16.h>
#include <stdint.h>

// Problem constants (B=2, L=2048, D=2048, E=8, Dg=256, k=2)
#define T_TOK 4096
#define DIM   2048
#define NEXP  8
#define DG    256
#define TOPK  2

// GEMM tiling: 128x128 tile, 4 waves x 64x64, BK=32, double-buffered LDS
#define BM 128
#define BN 128
#define BK 32
#define NROWS  (T_TOK*TOPK + NEXP*BM)   // 9216 padded row capacity
#define NBLK_M (NROWS/BM)               // 72 M-blocks
#define KSPLIT 8                        // down GEMM split-K (bf16 partials)

typedef __attribute__((ext_vector_type(8))) short short8;
typedef __attribute__((ext_vector_type(4))) float f32x4;

static __device__ __forceinline__ short f2bf(float f) {
    union { float f; uint32_t u; } v{f};
    uint32_t r = v.u + 0x7fffu + ((v.u >> 16) & 1u);   // RNE
    return (short)(r >> 16);
}
static __device__ __forceinline__ float b2f(short s) {
    union { uint32_t u; float f; } v{((uint32_t)(unsigned short)s) << 16};
    return v.f;
}

#define LDSP(p) ((__attribute__((address_space(3))) void*)(p))
#define GLD16(g, l) \
    __builtin_amdgcn_global_load_lds((const __attribute__((address_space(1))) void*)(g), LDSP(l), 16, 0, 0)

// ---------------------------------------------------------------------------
// Gate + x->bf16 + weight->bf16, all fused (pure-BW kernel, ~151 MB).
// One wave per token for the gate; each thread additionally converts
// 4 float4 of Wd and 4 of Wu (grid covers the weights exactly).
// ---------------------------------------------------------------------------
__global__ __launch_bounds__(256) void gate_kernel(const float* __restrict__ x,
                                                   const float* __restrict__ Wg,
                                                   const float* __restrict__ Wd,
                                                   const float* __restrict__ Wu,
                                                   int* __restrict__ gidx,
                                                   float* __restrict__ gval,
                                                   short* __restrict__ x_bf,
                                                   short* __restrict__ Wd_bf,
                                                   short* __restrict__ Wu_bf)
{
    int token = blockIdx.x * 4 + (threadIdx.x >> 6);
    int lane  = threadIdx.x & 63;
    const float4* xr = (const float4*)(x + (size_t)token * DIM);

    float4 xv[8];
#pragma unroll
    for (int i = 0; i < 8; i++) xv[i] = xr[lane + 64 * i];

    short4* xb = (short4*)(x_bf + (size_t)token * DIM);
#pragma unroll
    for (int i = 0; i < 8; i++) {
        short4 o;
        o.x = f2bf(xv[i].x); o.y = f2bf(xv[i].y);
        o.z = f2bf(xv[i].z); o.w = f2bf(xv[i].w);
        xb[lane + 64 * i] = o;
    }

    // weight conversion slice: 262144 threads x 4 float4 = 1048576 per tensor
    int wi = blockIdx.x * 256 + threadIdx.x;
#pragma unroll
    for (int ii = 0; ii < 4; ii++) {
        int j = wi + ii * 262144;
        float4 v = ((const float4*)Wd)[j];
        short4 o;
        o.x = f2bf(v.x); o.y = f2bf(v.y); o.z = f2bf(v.z); o.w = f2bf(v.w);
        ((short4*)Wd_bf)[j] = o;
        float4 u = ((const float4*)Wu)[j];
        short4 p;
        p.x = f2bf(u.x); p.y = f2bf(u.y); p.z = f2bf(u.z); p.w = f2bf(u.w);
        ((short4*)Wu_bf)[j] = p;
    }

    float acc[NEXP];
#pragma unroll
    for (int e = 0; e < NEXP; e++) {
        const float4* wr = (const float4*)(Wg + e * DIM);
        float a = 0.0f;
#pragma unroll
        for (int i = 0; i < 8; i++) {
            float4 w = wr[lane + 64 * i];
            a += xv[i].x * w.x + xv[i].y * w.y + xv[i].z * w.z + xv[i].w * w.w;
        }
        acc[e] = a;
    }

#pragma unroll
    for (int m = 1; m < 64; m <<= 1) {
#pragma unroll
        for (int e = 0; e < NEXP; e++) acc[e] += __shfl_xor(acc[e], m, 64);
    }

    if (lane == 0) {
        float sg[NEXP];
#pragma unroll
        for (int e = 0; e < NEXP; e++) sg[e] = 1.0f / (1.0f + expf(-acc[e]));
        int i0 = 0;
#pragma unroll
        for (int e = 1; e < NEXP; e++) if (sg[e] > sg[i0]) i0 = e;   // strict >: lowest index wins
        int i1 = (i0 == 0) ? 1 : 0;
#pragma unroll
        for (int e = 0; e < NEXP; e++) if (e != i0 && e != i1 && sg[e] > sg[i1]) i1 = e;
        gidx[2 * token + 0] = i0;
        gidx[2 * token + 1] = i1;
        gval[2 * token + 0] = sg[i0];
        gval[2 * token + 1] = sg[i1];
    }
}

// ---------------------------------------------------------------------------
// Bucket rows by expert (segments padded to BM=128); rowtok + rowpos.
// ---------------------------------------------------------------------------
__global__ __launch_bounds__(1024) void bucket_kernel(const int* __restrict__ gidx,
                                                      int* __restrict__ rowtok,
                                                      int* __restrict__ rowpos,
                                                      int* __restrict__ seg_off)
{
    __shared__ int cnt[NEXP];
    __shared__ int cur[NEXP];
    int tid = threadIdx.x;
    if (tid < NEXP) cnt[tid] = 0;
    __syncthreads();

    for (int t = tid; t < T_TOK; t += 1024) {
        atomicAdd(&cnt[gidx[2 * t + 0]], 1);
        atomicAdd(&cnt[gidx[2 * t + 1]], 1);
    }
    __syncthreads();

    if (tid == 0) {
        int o = 0;
        for (int e = 0; e < NEXP; e++) {
            seg_off[e] = o;
            cur[e] = o;
            o += ((cnt[e] + BM - 1) / BM) * BM;
        }
        seg_off[NEXP] = o;
    }
    __syncthreads();

    for (int r = tid; r < NROWS; r += 1024) rowtok[r] = -1;
    __syncthreads();

    for (int t = tid; t < T_TOK; t += 1024) {
        for (int s = 0; s < TOPK; s++) {
            int e = gidx[2 * t + s];
            int p = atomicAdd(&cur[e], 1);
            rowtok[p] = t;
            rowpos[2 * t + s] = p;
        }
    }
}

// ---------------------------------------------------------------------------
// Grouped GEMM (bf16 MFMA), 128x128 tile, double-buffered LDS, swapped-operand
// MFMA so each lane holds 4 consecutive N-columns (8B stores).
//   C[kb][row][n] = sum_{k in kb-chunk} A[rowtok[row]][k] * B[e][n][k]   (bf16)
// Staging: GLD16 both operands (per-lane gaddr, wave-uniform LDS dest).
// XOR 16B-chunk swizzle keeps ds_read_b128 fragment reads <=2-way (free).
// ---------------------------------------------------------------------------
template<int K, int KC, int Ntot>
__global__ __launch_bounds__(256) void gemm_kernel(const short* __restrict__ A,
                                                   const short* __restrict__ B,
                                                   const int* __restrict__ rowtok,
                                                   const int* __restrict__ seg_off,
                                                   short* __restrict__ C)
{
    __shared__ short As[2][BM][BK];   // 16 KB
    __shared__ short Bs[2][BN][BK];   // 16 KB

    int row0 = blockIdx.x * BM;
    if (row0 >= seg_off[NEXP]) return;
    int e = 0;
    while (row0 >= seg_off[e + 1]) ++e;   // BM-padded segments: block in one expert
    int n0 = blockIdx.y * BN;
    int kb = blockIdx.z;
    int ks = kb * KC;

    int tid = threadIdx.x;
    int w = tid >> 6, l = tid & 63;

    // ---- staging addresses: lane (r,c) loads global chunk c^((r>>1)&3) of
    //      rows {w*16+r, 64+w*16+r}; GLD16 dest = wave row-block base ----
    int r = l >> 2, c = l & 3;
    int gch = c ^ ((r >> 1) & 3);
    int ar0 = w * 16 + r, ar1 = 64 + w * 16 + r;
    int ta0 = rowtok[row0 + ar0]; if (ta0 < 0) ta0 = 0;
    int ta1 = rowtok[row0 + ar1]; if (ta1 < 0) ta1 = 0;
    const short* ag0 = A + (size_t)ta0 * K + ks + gch * 8;
    const short* ag1 = A + (size_t)ta1 * K + ks + gch * 8;
    const short* bb  = B + (size_t)e * Ntot * K + (size_t)n0 * K + ks + gch * 8;
    const short* bg0 = bb + (size_t)ar0 * K;
    const short* bg1 = bb + (size_t)ar1 * K;

    // ---- fragment read addresses ----
    int mlane = l & 15, q = l >> 4;
    int rA = (q ^ ((mlane >> 1) & 3)) * 8;   // swizzled 16B chunk (in shorts)
    int wm = w >> 1, wn = w & 1;

    f32x4 acc[4][4] = {};

    constexpr int NS = KC / BK;
    // prologue: stage buffer 0
    GLD16(ag0, &As[0][w * 16][0]);
    GLD16(ag1, &As[0][64 + w * 16][0]);
    GLD16(bg0, &Bs[0][w * 16][0]);
    GLD16(bg1, &Bs[0][64 + w * 16][0]);

    for (int t = 0; t < NS; ++t) {
        __syncthreads();   // drains stage(t) vmcnt; releases buf[t^1] for restaging
        if (t + 1 < NS) {
            int nb = (t + 1) & 1;
            int ko = (t + 1) * BK;
            GLD16(ag0 + ko, &As[nb][w * 16][0]);
            GLD16(ag1 + ko, &As[nb][64 + w * 16][0]);
            GLD16(bg0 + ko, &Bs[nb][w * 16][0]);
            GLD16(bg1 + ko, &Bs[nb][64 + w * 16][0]);
        }
        int cb = t & 1;
        const short* pa = &As[cb][wm * 64 + mlane][0] + rA;
        const short* pb = &Bs[cb][wn * 64 + mlane][0] + rA;
        short8 a[4], b[4];
#pragma unroll
        for (int i = 0; i < 4; i++) a[i] = *(const short8*)(pa + i * 16 * BK);
#pragma unroll
        for (int j = 0; j < 4; j++) b[j] = *(const short8*)(pb + j * 16 * BK);

        // swapped operands: lane(q,mlane) reg rr -> C[m=i*16+mlane][n=j*16+q*4+rr]
#pragma unroll
        for (int i = 0; i < 4; i++)
#pragma unroll
            for (int j = 0; j < 4; j++)
                acc[i][j] = __builtin_amdgcn_mfma_f32_16x16x32_bf16(b[j], a[i], acc[i][j], 0, 0, 0);
    }

    // epilogue: 16x 8B stores per lane (4 consecutive n per reg quad)
#pragma unroll
    for (int i = 0; i < 4; i++) {
        size_t grow = (size_t)kb * NROWS + row0 + wm * 64 + i * 16 + mlane;
        short* crow = C + grow * Ntot + n0 + wn * 64 + q * 4;
#pragma unroll
        for (int j = 0; j < 4; j++) {
            short4 v;
            v.x = f2bf(acc[i][j][0]); v.y = f2bf(acc[i][j][1]);
            v.z = f2bf(acc[i][j][2]); v.w = f2bf(acc[i][j][3]);
            *(short4*)(crow + j * 16) = v;
        }
    }
}

// ---------------------------------------------------------------------------
// Combine down partials (8 bf16 planes) -> per-token down, emit bf16.
// One wave per token; lane = short4 column chunk (64 x 4 = 256 = DG).
// ---------------------------------------------------------------------------
__global__ __launch_bounds__(256) void combine1_kernel(const short* __restrict__ P,
                                                       const int* __restrict__ rowpos,
                                                       const float* __restrict__ gval,
                                                       short* __restrict__ dt)
{
    int t = blockIdx.x * 4 + (threadIdx.x >> 6);
    int d = threadIdx.x & 63;
    int   p0 = rowpos[2 * t], p1 = rowpos[2 * t + 1];
    float g0 = gval[2 * t],   g1 = gval[2 * t + 1];
    const short4* P4 = (const short4*)P;
    const size_t plane = (size_t)NROWS * DG / 4;

    float s0 = 0, s1 = 0, s2 = 0, s3 = 0;
#pragma unroll
    for (int kb = 0; kb < KSPLIT; kb++) {
        short4 a = P4[kb * plane + (size_t)p0 * (DG / 4) + d];
        short4 b = P4[kb * plane + (size_t)p1 * (DG / 4) + d];
        s0 += g0 * b2f(a.x) + g1 * b2f(b.x);
        s1 += g0 * b2f(a.y) + g1 * b2f(b.y);
        s2 += g0 * b2f(a.z) + g1 * b2f(b.z);
        s3 += g0 * b2f(a.w) + g1 * b2f(b.w);
    }
    short4 o;
    o.x = f2bf(s0); o.y = f2bf(s1); o.z = f2bf(s2); o.w = f2bf(s3);
    ((short4*)(dt + (size_t)t * DG))[d] = o;
}

// ---------------------------------------------------------------------------
// Combine up rows -> final output (fp32).
// ---------------------------------------------------------------------------
__global__ __launch_bounds__(256) void combine2_kernel(const short* __restrict__ ur,
                                                       const int* __restrict__ rowpos,
                                                       const float* __restrict__ gval,
                                                       float* __restrict__ out)
{
    int i = blockIdx.x * 256 + threadIdx.x;       // i < T*D/4
    int t = i >> 9;                               // D/4 = 512
    int c = (i & 511) * 4;
    int   p0 = rowpos[2 * t], p1 = rowpos[2 * t + 1];
    float g0 = gval[2 * t],   g1 = gval[2 * t + 1];
    short4 u0 = *(const short4*)&ur[(size_t)p0 * DIM + c];
    short4 u1 = *(const short4*)&ur[(size_t)p1 * DIM + c];
    float4 o;
    o.x = g0 * b2f(u0.x) + g1 * b2f(u1.x);
    o.y = g0 * b2f(u0.y) + g1 * b2f(u1.y);
    o.z = g0 * b2f(u0.z) + g1 * b2f(u1.z);
    o.w = g0 * b2f(u0.w) + g1 * b2f(u1.w);
    *(float4*)&out[(size_t)t * DIM + c] = o;
}

// ---------------------------------------------------------------------------
// Workspace (bytes), ~111 MB total:
//   gidx 0 | gval 32768 | rowtok 65536 | rowpos 102400 | seg_off 135168
//   x_bf 135424 (16.8M) | Wd_bf 16912640 (8.4M) | Wu_bf 25301248 (8.4M)
//   P 33689856 (37.7M bf16, 8 planes) | dt_bf 71438592 (2M) | ur_bf 73535744 (37.7M)
// ---------------------------------------------------------------------------
extern "C" void kernel_launch(void* const* d_in, const int* in_sizes, int n_in,
                              void* d_out, int out_size, void* d_ws, size_t ws_size,
                              hipStream_t stream) {
    const float* x  = (const float*)d_in[0];
    const float* Wg = (const float*)d_in[1];
    const float* Wd = (const float*)d_in[2];
    const float* Wu = (const float*)d_in[3];
    float* out = (float*)d_out;

    char* p = (char*)d_ws;
    int*   gidx    = (int*)(p + 0);
    float* gval    = (float*)(p + 32768);
    int*   rowtok  = (int*)(p + 65536);
    int*   rowpos  = (int*)(p + 102400);
    int*   seg_off = (int*)(p + 135168);
    short* x_bf    = (short*)(p + 135424);
    short* Wd_bf   = (short*)(p + 16912640);
    short* Wu_bf   = (short*)(p + 25301248);
    short* P       = (short*)(p + 33689856);
    short* dt_bf   = (short*)(p + 71438592);
    short* ur_bf   = (short*)(p + 73535744);

    gate_kernel<<<T_TOK / 4, 256, 0, stream>>>(x, Wg, Wd, Wu, gidx, gval, x_bf, Wd_bf, Wu_bf);
    bucket_kernel<<<1, 1024, 0, stream>>>(gidx, rowtok, rowpos, seg_off);

    // down: M=9216, N=256, K=2048, split-K=8 -> bf16 partial planes
    gemm_kernel<DIM, DIM / KSPLIT, DG>
        <<<dim3(NBLK_M, DG / BN, KSPLIT), 256, 0, stream>>>(x_bf, Wd_bf, rowtok, seg_off, P);
    combine1_kernel<<<T_TOK / 4, 256, 0, stream>>>(P, rowpos, gval, dt_bf);

    // up: M=9216, N=2048, K=256 -> bf16 rows
    gemm_kernel<DG, DG, DIM>
        <<<dim3(NBLK_M, DIM / BN, 1), 256, 0, stream>>>(dt_bf, Wu_bf, rowtok, seg_off, ur_bf);
    combine2_kernel<<<T_TOK * DIM / 4 / 256, 256, 0, stream>>>(ur_bf, rowpos, gval, out);
}